// Round 15
// baseline (147.487 us; speedup 1.0000x reference)
//
#include <hip/hip_runtime.h>

#define CF 768
#define CCODE 70
#define NPIX 784
#define P 121
#define NB 32
#define NTOTF 468512.0f

#define OFF_PI_SCALAR 0
#define OFF_PI_CD 1
#define OFF_PO_SCALAR 468513
#define OFF_PO_CD 468514
#define OFF_NEG_LOSS 937026
#define OFF_NEG_CD 3279586

// ---- ws layout (floats) ----
#define WS_BSUMS 0              // 448*3
#define WS_ADDT 1536            // 5
#define WS_NSQF 2048            // 8 slots * 32 n * 12 sub * 128 pt = 393216
#define WS_NSQC 395264          // 7 slots * 32 n * 128 pt = 28672
#define WS_FRAG_FLOAT 423936    // bf16 fragment region
#define FEAT_FRAG_SHORTS 98304  // 24 panels * 8 tiles * 64 lanes * 8
#define CODE_FRAG_SHORTS 12288  // 3 panels * 8 * 64 * 8
#define FEATS_TOTAL_SHORTS (8 * 32 * FEAT_FRAG_SHORTS)
#define CODE_BASE_SHORTS FEATS_TOTAL_SHORTS
#define CODE_TOTAL_SHORTS (7 * 32 * CODE_FRAG_SHORTS)
#define WS_NEED2 (WS_FRAG_FLOAT + (FEATS_TOTAL_SHORTS + CODE_TOTAL_SHORTS) / 2)

typedef __attribute__((ext_vector_type(8))) short short8;
typedef __attribute__((ext_vector_type(4))) float f32x4;
typedef unsigned short ushort_t;
typedef unsigned int uint_t;

__device__ __forceinline__ float samp4(const float* __restrict__ img, int c,
                                       const int4 o, const float4 w) {
  const float* p = img + c * NPIX;
  return w.x * p[o.x] + w.y * p[o.y] + w.z * p[o.z] + w.w * p[o.w];
}

__device__ __forceinline__ void mkcoord(const float* cp, int4* o, float4* w) {
  float x = fminf(fmaxf(cp[0] * 27.f, 0.f), 27.f);
  float y = fminf(fmaxf(cp[1] * 27.f, 0.f), 27.f);
  float x0f = floorf(x), y0f = floorf(y);
  int x0 = (int)x0f, y0 = (int)y0f;
  int x1 = min(x0 + 1, 27), y1 = min(y0 + 1, 27);
  float wx = x - x0f, wy = y - y0f;
  *o = make_int4(y0 * 28 + x0, y0 * 28 + x1, y1 * 28 + x0, y1 * 28 + x1);
  *w = make_float4((1.f - wx) * (1.f - wy), wx * (1.f - wy),
                   (1.f - wx) * wy, wx * wy);
}

// pair-based coords: o = (row0 base, row1 base), w = (wa0, wa1, wb0, wb1)
__device__ __forceinline__ void mkcoord2(const float* cp, int2* o, float4* w) {
  float x = fminf(fmaxf(cp[0] * 27.f, 0.f), 27.f);
  float y = fminf(fmaxf(cp[1] * 27.f, 0.f), 27.f);
  float x0f = floorf(x), y0f = floorf(y);
  int x0 = (int)x0f, y0 = (int)y0f;
  int y1 = min(y0 + 1, 27);
  float wx = x - x0f, wy = y - y0f;
  bool sh = (x0 >= 27);
  int xb = sh ? 26 : x0;
  float wa0 = sh ? 0.f : (1.f - wx) * (1.f - wy);
  float wa1 = sh ? (1.f - wy) : wx * (1.f - wy);
  float wb0 = sh ? 0.f : (1.f - wx) * wy;
  float wb1 = sh ? wy : wx * wy;
  *o = make_int2(y0 * 28 + xb, y1 * 28 + xb);
  *w = make_float4(wa0, wa1, wb0, wb1);
}

__device__ __forceinline__ ushort_t f2bf(float x) {
  uint_t u = __float_as_uint(x);
  u += 0x7fffu + ((u >> 16) & 1u);
  return (ushort_t)(u >> 16);
}

// ===================== presample: counted-vmcnt 3-deep DMA pipeline =========
// Feat blocks (95% of work, all octets full-valid): triple-buffered
// global_load_lds with COUNTED s_waitcnt vmcnt(N) (never 0 in steady state) +
// raw s_barrier — loads stay in flight across barriers (T3/T4), removing the
// per-phase vmcnt(0) drain that __syncthreads imposes (shared by all prior
// neutral variants). N derivation (per-wave-uniform): each STAGE issues 6
// (waves 1-3) or 7 (wave 0) loads; frag stores only make vmcnt stricter.
// Steady state: wait vmcnt(12) drains octet-g's loads; tail: 6 then 0.
// Code blocks (tensors 3/4: partial octets) keep the verified __syncthreads
// double-buffer path.
// Per-thread (slot, coord, frag-base, nsq-index) hoisted (R12+); sumsq
// partials fused (R13). jobs: [0,384) OF G=8; [384,768) DAF; [768,1152) OFP;
// [1152,1184) OC G=12; [1184,1216) OCP G=12.
__global__ __launch_bounds__(256) void presample_p3(
    const float* __restrict__ OF, const float* __restrict__ OFP,
    const float* __restrict__ OC, const float* __restrict__ OCP,
    const float* __restrict__ DAF,
    const float* __restrict__ CO1, const float* __restrict__ CO2,
    const int* __restrict__ PERMS, float* __restrict__ ws) {
  ushort_t* frags = (ushort_t*)(ws + WS_FRAG_FLOAT);
  __shared__ float planes[3 * 8 * NPIX];  // 75264 B
  __shared__ int sh_slot[16], sh_n[16], sh_cb[16];
  __shared__ int sh_ncs;
  const int job = (int)(((long long)blockIdx.x * 405) % 1216);
  const int tid = threadIdx.x;
  const int wv64 = tid >> 6;

  int tensor, m, g0, G;
  if (job < 384) { tensor = 0; m = job / 12; g0 = (job - m * 12) * 8; G = 8; }
  else if (job < 768) { int j = job - 384; tensor = 1; m = j / 12; g0 = (j - m * 12) * 8; G = 8; }
  else if (job < 1152) { int j = job - 768; tensor = 2; m = j / 12; g0 = (j - m * 12) * 8; G = 8; }
  else if (job < 1184) { tensor = 3; m = job - 1152; g0 = 0; G = 12; }
  else { tensor = 4; m = job - 1184; g0 = 0; G = 12; }

  const float* src;
  int nch;
  bool feat;
  if (tensor == 0) { src = OF + (size_t)m * CF * NPIX; nch = CF; feat = true; }
  else if (tensor == 1) { src = DAF + (size_t)m * CF * NPIX; nch = CF; feat = true; }
  else if (tensor == 2) { src = OFP + (size_t)m * CF * NPIX; nch = CF; feat = true; }
  else if (tensor == 3) { src = OC + (size_t)m * CCODE * NPIX; nch = CCODE; feat = false; }
  else { src = OCP + (size_t)m * CCODE * NPIX; nch = CCODE; feat = false; }

  // DMA-stage a full-valid octet (6 or 7 loads per thread, lane-linear dest)
#define STAGE_DMA(OCT, PLP)                                                   \
  {                                                                           \
    const float4* sc_ = (const float4*)(src + (size_t)(OCT) * 8 * NPIX);      \
    float4* pb_ = (float4*)(PLP);                                             \
    _Pragma("unroll") for (int k_ = 0; k_ < 6; ++k_) {                        \
      __builtin_amdgcn_global_load_lds(                                       \
          (const __attribute__((address_space(1))) uint_t*)(const void*)      \
              (sc_ + k_ * 256 + tid),                                         \
          (__attribute__((address_space(3))) uint_t*)(void*)                  \
              (pb_ + k_ * 256 + wv64 * 64),                                   \
          16, 0, 0);                                                          \
    }                                                                         \
    if (tid < 32) {                                                           \
      __builtin_amdgcn_global_load_lds(                                       \
          (const __attribute__((address_space(1))) uint_t*)(const void*)      \
              (sc_ + 1536 + tid),                                             \
          (__attribute__((address_space(3))) uint_t*)(void*)(pb_ + 1536),     \
          16, 0, 0);                                                          \
    }                                                                         \
  }

  // Generic stage (manual zero-fill for partial/invalid octets; code path)
#define STAGE_ANY(OCT, PLP)                                                   \
  {                                                                           \
    const int c0_ = (OCT) * 8;                                                \
    const float4* sc_ = (const float4*)(src + (size_t)c0_ * NPIX);            \
    float4* pb_ = (float4*)(PLP);                                             \
    if (c0_ + 8 <= nch) {                                                     \
      STAGE_DMA(OCT, PLP)                                                     \
    } else {                                                                  \
      int valid_ = nch - c0_;                                                 \
      valid_ = valid_ > 8 ? 8 : (valid_ < 0 ? 0 : valid_);                    \
      const int lim4_ = valid_ * (NPIX / 4);                                  \
      _Pragma("unroll") for (int k_ = 0; k_ < 7; ++k_) {                      \
        const int e_ = tid + k_ * 256;                                        \
        if (e_ < 1568)                                                        \
          pb_[e_] = (e_ < lim4_) ? sc_[e_] : make_float4(0.f, 0.f, 0.f, 0.f); \
      }                                                                       \
    }                                                                         \
  }

  // ---- coordset list (thread 0); full barrier cleans the vmem slate ----
  if (tid == 0) {
    int cnt = 0;
    if (tensor == 0) {
      sh_slot[0] = 1; sh_n[0] = m; sh_cb[0] = 0; cnt = 1;
      for (int i = 0; i < 5; ++i)
        for (int k = 0; k < NB; ++k)
          if (PERMS[i * NB + k] == m) {
            sh_slot[cnt] = 3 + i; sh_n[cnt] = k; sh_cb[cnt] = 1; ++cnt;
          }
    } else if (tensor == 1) { sh_slot[0] = 0; sh_n[0] = m; sh_cb[0] = 0; cnt = 1; }
    else if (tensor == 2) { sh_slot[0] = 2; sh_n[0] = m; sh_cb[0] = 1; cnt = 1; }
    else if (tensor == 3) {
      sh_slot[0] = 0; sh_n[0] = m; sh_cb[0] = 0; cnt = 1;
      for (int i = 0; i < 5; ++i)
        for (int k = 0; k < NB; ++k)
          if (PERMS[i * NB + k] == m) {
            sh_slot[cnt] = 2 + i; sh_n[cnt] = k; sh_cb[cnt] = 1; ++cnt;
          }
    } else { sh_slot[0] = 1; sh_n[0] = m; sh_cb[0] = 1; cnt = 1; }
    sh_ncs = cnt;
  }
  __syncthreads();  // publish sh list; drains all prior vmem (clean slate)

  // ---- hoist per-thread slot state (coord loads retire via use) ----
  const int total = sh_ncs * 128;
  const int sub = g0 >> 3;
  int2 o_0, o_1, o_2, o_3, o_4, o_5;
  float4 w_0, w_1, w_2, w_3, w_4, w_5;
  uint_t b_0 = 0, b_1 = 0, b_2 = 0, b_3 = 0, b_4 = 0, b_5 = 0;
  uint_t nq_0 = 0, nq_1 = 0, nq_2 = 0, nq_3 = 0, nq_4 = 0, nq_5 = 0;
  float sq_0 = 0.f, sq_1 = 0.f, sq_2 = 0.f, sq_3 = 0.f, sq_4 = 0.f, sq_5 = 0.f;
#define SETUP_SLOT(J, OV, WV, BV, NQV)                                       \
  {                                                                          \
    const int s_ = tid + (J) * 256;                                          \
    OV = make_int2(0, 0);                                                    \
    WV = make_float4(0.f, 0.f, 0.f, 0.f);                                    \
    if (s_ < total) {                                                        \
      const int cs_ = s_ >> 7, pt_ = s_ & 127;                               \
      const int slot_ = sh_slot[cs_], n_ = sh_n[cs_];                        \
      const float* cb_ = sh_cb[cs_] ? CO2 : CO1;                             \
      size_t fb_ = feat ? (size_t)(slot_ * 32 + n_) * FEAT_FRAG_SHORTS       \
                        : CODE_BASE_SHORTS +                                 \
                              (size_t)(slot_ * 32 + n_) * CODE_FRAG_SHORTS;  \
      BV = (uint_t)(fb_ + ((size_t)((pt_ >> 4) * 64 + (pt_ & 15)) << 3));    \
      NQV = feat ? (uint_t)(WS_NSQF +                                        \
                            ((slot_ * 32 + n_) * 12 + sub) * 128 + pt_)      \
                 : (uint_t)(WS_NSQC + (slot_ * 32 + n_) * 128 + pt_);        \
      if (pt_ < P) {                                                         \
        int gi_ = pt_ / 11, gj_ = pt_ - gi_ * 11;                            \
        mkcoord2(cb_ + (((n_ * 11 + gj_) * 11 + gi_) << 1), &OV, &WV);       \
      }                                                                      \
    }                                                                        \
  }
  SETUP_SLOT(0, o_0, w_0, b_0, nq_0)
  SETUP_SLOT(1, o_1, w_1, b_1, nq_1)
  SETUP_SLOT(2, o_2, w_2, b_2, nq_2)
  SETUP_SLOT(3, o_3, w_3, b_3, nq_3)
  SETUP_SLOT(4, o_4, w_4, b_4, nq_4)
  SETUP_SLOT(5, o_5, w_5, b_5, nq_5)
#undef SETUP_SLOT

#define DO_SLOT(J, OV, WV, BV, SQV)                                          \
  if (tid + (J) * 256 < total) {                                             \
    float v_[8];                                                             \
    _Pragma("unroll") for (int i_ = 0; i_ < 8; ++i_) {                       \
      const float* pl_ = PL + i_ * NPIX;                                     \
      v_[i_] = WV.x * pl_[OV.x] + WV.y * pl_[OV.x + 1] +                     \
               WV.z * pl_[OV.y] + WV.w * pl_[OV.y + 1];                      \
      SQV = fmaf(v_[i_], v_[i_], SQV);                                       \
    }                                                                        \
    uint4 q_;                                                                \
    q_.x = (uint_t)f2bf(v_[0]) | ((uint_t)f2bf(v_[1]) << 16);                \
    q_.y = (uint_t)f2bf(v_[2]) | ((uint_t)f2bf(v_[3]) << 16);                \
    q_.z = (uint_t)f2bf(v_[4]) | ((uint_t)f2bf(v_[5]) << 16);                \
    q_.w = (uint_t)f2bf(v_[6]) | ((uint_t)f2bf(v_[7]) << 16);                \
    *(uint4*)(frags + BV + octoff) = q_;                                     \
  }

  if (feat) {
    // ---- 3-deep counted-vmcnt pipeline (G=8, all octets full-valid) ----
    STAGE_DMA(g0 + 0, planes);
    STAGE_DMA(g0 + 1, planes + 8 * NPIX);
#pragma unroll 1
    for (int g = 0; g < 8; ++g) {
      const int o = g0 + g;
      const float* PL = planes + (g % 3) * 8 * NPIX;
      if (g + 2 < 8) {
        float* PN = planes + ((g + 2) % 3) * 8 * NPIX;
        STAGE_DMA(g0 + g + 2, PN);
      }
      // wait only octet-g's loads (6/7 per wave); stores make this stricter
      if (g < 6) {
        asm volatile("s_waitcnt vmcnt(12)" ::: "memory");
      } else if (g == 6) {
        asm volatile("s_waitcnt vmcnt(6)" ::: "memory");
      } else {
        asm volatile("s_waitcnt vmcnt(0)" ::: "memory");
      }
      __builtin_amdgcn_sched_barrier(0);
      __builtin_amdgcn_s_barrier();  // all waves' DMA for buf g visible

      const uint_t octoff = (uint_t)((o >> 2) * 4096 + (o & 3) * 128);
      DO_SLOT(0, o_0, w_0, b_0, sq_0)
      DO_SLOT(1, o_1, w_1, b_1, sq_1)
      DO_SLOT(2, o_2, w_2, b_2, sq_2)
      DO_SLOT(3, o_3, w_3, b_3, sq_3)
      DO_SLOT(4, o_4, w_4, b_4, sq_4)
      DO_SLOT(5, o_5, w_5, b_5, sq_5)
      asm volatile("" ::: "memory");
      __builtin_amdgcn_s_barrier();  // release buf g for re-stage
    }
  } else {
    // ---- code path: verified double-buffer with __syncthreads ----
    STAGE_ANY(0, planes);
#pragma unroll 1
    for (int g = 0; g < 12; ++g) {
      const int o = g;
      const float* PL = planes + (g & 1) * 8 * NPIX;
      float* PN = planes + ((g + 1) & 1) * 8 * NPIX;
      if (g == 0) __syncthreads();  // first buffer ready
      if (g + 1 < 12) STAGE_ANY(g + 1, PN);
      const uint_t octoff = (uint_t)((o >> 2) * 4096 + (o & 3) * 128);
      DO_SLOT(0, o_0, w_0, b_0, sq_0)
      DO_SLOT(1, o_1, w_1, b_1, sq_1)
      DO_SLOT(2, o_2, w_2, b_2, sq_2)
      DO_SLOT(3, o_3, w_3, b_3, sq_3)
      DO_SLOT(4, o_4, w_4, b_4, sq_4)
      DO_SLOT(5, o_5, w_5, b_5, sq_5)
      __syncthreads();  // drain next-octet stage + release PL
    }
  }
#undef DO_SLOT
#undef STAGE_ANY
#undef STAGE_DMA

  // ---- write per-slot sumsq partials (each written exactly once) ----
  if (tid < total) ws[nq_0] = sq_0;
  if (tid + 256 < total) ws[nq_1] = sq_1;
  if (tid + 512 < total) ws[nq_2] = sq_2;
  if (tid + 768 < total) ws[nq_3] = sq_3;
  if (tid + 1024 < total) ws[nq_4] = sq_4;
  if (tid + 1280 < total) ws[nq_5] = sq_5;
}

// ===================== MFMA Gram (448 blocks = pairn x 2 row-halves) ========
__global__ __launch_bounds__(256) void gram_mfma2(float* __restrict__ ws,
                                                  float* __restrict__ out) {
  const ushort_t* frags = (const ushort_t*)(ws + WS_FRAG_FLOAT);
  const int bid = blockIdx.x;
  const int half = bid & 1, pairn = bid >> 1;
  const int pair = pairn >> 5, n = pairn & 31;
  const int tid = threadIdx.x, wave = tid >> 6, lane = tid & 63;
  __shared__ float invAf[128], invBf[128], invAc[128], invBc[128];
  __shared__ float red[4][3];
  const int afslot = (pair == 0) ? 0 : 1;
  const int bfslot = (pair == 0) ? 0 : (pair == 1 ? 2 : 3 + (pair - 2));
  const int bcslot = (pair == 0) ? 0 : (pair == 1 ? 1 : 2 + (pair - 2));
  if (tid < 128) {
    float s;
    const float* p;
    p = ws + WS_NSQF + (size_t)(afslot * 32 + n) * 12 * 128 + tid;
    s = 0.f;
#pragma unroll
    for (int u = 0; u < 12; ++u) s += p[u * 128];
    invAf[tid] = 1.f / fmaxf(sqrtf(s), 1e-10f);
    p = ws + WS_NSQF + (size_t)(bfslot * 32 + n) * 12 * 128 + tid;
    s = 0.f;
#pragma unroll
    for (int u = 0; u < 12; ++u) s += p[u * 128];
    invBf[tid] = 1.f / fmaxf(sqrtf(s), 1e-10f);
    invAc[tid] = 1.f / fmaxf(sqrtf(ws[WS_NSQC + (0 * 32 + n) * 128 + tid]), 1e-10f);
    invBc[tid] = 1.f / fmaxf(sqrtf(ws[WS_NSQC + (bcslot * 32 + n) * 128 + tid]), 1e-10f);
  }
  __syncthreads();

  const short8* Af = (const short8*)(frags + (size_t)(afslot * 32 + n) * FEAT_FRAG_SHORTS);
  const short8* Bf = (const short8*)(frags + (size_t)(bfslot * 32 + n) * FEAT_FRAG_SHORTS);
  const int rt = half * 4 + wave;  // row-tile 0..7

  f32x4 acc[8];
#pragma unroll
  for (int t = 0; t < 8; ++t) acc[t] = (f32x4){0.f, 0.f, 0.f, 0.f};

#pragma unroll 2
  for (int kp = 0; kp < 24; ++kp) {
    short8 a0 = Af[(kp * 8 + rt) * 64 + lane];
    short8 bv[8];
#pragma unroll
    for (int t = 0; t < 8; ++t) bv[t] = Bf[(kp * 8 + t) * 64 + lane];
#pragma unroll
    for (int t = 0; t < 8; ++t)
      acc[t] = __builtin_amdgcn_mfma_f32_16x16x32_bf16(a0, bv[t], acc[t], 0, 0, 0);
  }

  const int lane4 = (lane >> 4) << 2;
  const int cl15 = lane & 15;
  const int rb = rt * 16 + lane4;
  float sfd = 0.f;
  {
    const float ivr0 = invAf[rb], ivr1 = invAf[rb + 1], ivr2 = invAf[rb + 2],
                ivr3 = invAf[rb + 3];
    float rs0 = 0.f, rs1 = 0.f, rs2 = 0.f, rs3 = 0.f;
#pragma unroll
    for (int t = 0; t < 8; ++t) {
      const float ivc = invBf[t * 16 + cl15];
      float v0 = acc[t].x * ivr0 * ivc;
      float v1 = acc[t].y * ivr1 * ivc;
      float v2 = acc[t].z * ivr2 * ivc;
      float v3 = acc[t].w * ivr3 * ivc;
      acc[t].x = v0; acc[t].y = v1; acc[t].z = v2; acc[t].w = v3;
      rs0 += v0; rs1 += v1; rs2 += v2; rs3 += v3;
    }
    sfd = rs0 + rs1 + rs2 + rs3;
    rs0 += __shfl_xor(rs0, 1); rs0 += __shfl_xor(rs0, 2);
    rs0 += __shfl_xor(rs0, 4); rs0 += __shfl_xor(rs0, 8);
    rs1 += __shfl_xor(rs1, 1); rs1 += __shfl_xor(rs1, 2);
    rs1 += __shfl_xor(rs1, 4); rs1 += __shfl_xor(rs1, 8);
    rs2 += __shfl_xor(rs2, 1); rs2 += __shfl_xor(rs2, 2);
    rs2 += __shfl_xor(rs2, 4); rs2 += __shfl_xor(rs2, 8);
    rs3 += __shfl_xor(rs3, 1); rs3 += __shfl_xor(rs3, 2);
    rs3 += __shfl_xor(rs3, 4); rs3 += __shfl_xor(rs3, 8);
    const float rm0 = rs0 * (1.f / 121.f), rm1 = rs1 * (1.f / 121.f);
    const float rm2 = rs2 * (1.f / 121.f), rm3 = rs3 * (1.f / 121.f);
#pragma unroll
    for (int t = 0; t < 8; ++t) {
      acc[t].x -= rm0; acc[t].y -= rm1; acc[t].z -= rm2; acc[t].w -= rm3;
    }
  }

  int cd_base, loss_base = 0;
  if (pair == 0) cd_base = OFF_PI_CD + n * 14641;
  else if (pair == 1) cd_base = OFF_PO_CD + n * 14641;
  else {
    int t0 = ((pair - 2) * NB + n) * 14641;
    cd_base = OFF_NEG_CD + t0;
    loss_base = OFF_NEG_LOSS + t0;
  }

  if (pair >= 2 && rb < P) {
#pragma unroll
    for (int t = 0; t < 8; ++t) {
      const int c = t * 16 + cl15;
      if (c < P) {
        float* o = out + loss_base + rb * P + c;
        o[0] = acc[t].x;
        if (rb + 1 < P) o[P] = acc[t].y;
        if (rb + 2 < P) o[2 * P] = acc[t].z;
        if (rb + 3 < P) o[3 * P] = acc[t].w;
      }
    }
  }

  // ---- code Gram (this half's rows) ----
  const short8* Ac = (const short8*)(frags + CODE_BASE_SHORTS + (size_t)n * CODE_FRAG_SHORTS);
  const short8* Bc = (const short8*)(frags + CODE_BASE_SHORTS + (size_t)(bcslot * 32 + n) * CODE_FRAG_SHORTS);
  f32x4 cacc[8];
#pragma unroll
  for (int t = 0; t < 8; ++t) cacc[t] = (f32x4){0.f, 0.f, 0.f, 0.f};
#pragma unroll
  for (int kp = 0; kp < 3; ++kp) {
    short8 a0 = Ac[(kp * 8 + rt) * 64 + lane];
    short8 bv[8];
#pragma unroll
    for (int t = 0; t < 8; ++t) bv[t] = Bc[(kp * 8 + t) * 64 + lane];
#pragma unroll
    for (int t = 0; t < 8; ++t)
      cacc[t] = __builtin_amdgcn_mfma_f32_16x16x32_bf16(a0, bv[t], cacc[t], 0, 0, 0);
  }

  float s1 = 0.f, s2 = 0.f;
  {
    const float ivr0 = invAc[rb], ivr1 = invAc[rb + 1], ivr2 = invAc[rb + 2],
                ivr3 = invAc[rb + 3];
#pragma unroll
    for (int t = 0; t < 8; ++t) {
      const int c = t * 16 + cl15;
      const float ivc = invBc[c];
      float c0v = cacc[t].x * ivr0 * ivc;
      float c1v = cacc[t].y * ivr1 * ivc;
      float c2v = cacc[t].z * ivr2 * ivc;
      float c3v = cacc[t].w * ivr3 * ivc;
      if (c < P && rb < P) {
        float* o = out + cd_base + rb * P + c;
        o[0] = c0v;
        if (rb + 1 < P) o[P] = c1v;
        if (rb + 2 < P) o[2 * P] = c2v;
        if (rb + 3 < P) o[3 * P] = c3v;
      }
      if (pair < 2) {
        float cl0 = fminf(fmaxf(c0v, 0.f), 0.8f);
        float cl1 = fminf(fmaxf(c1v, 0.f), 0.8f);
        float cl2 = fminf(fmaxf(c2v, 0.f), 0.8f);
        float cl3 = fminf(fmaxf(c3v, 0.f), 0.8f);
        s1 = fmaf(cl0, acc[t].x, s1);
        s1 = fmaf(cl1, acc[t].y, s1);
        s1 = fmaf(cl2, acc[t].z, s1);
        s1 = fmaf(cl3, acc[t].w, s1);
        s2 += cl0 + cl1 + cl2 + cl3;
      }
    }
  }

#pragma unroll
  for (int m = 1; m < 64; m <<= 1) {
    sfd += __shfl_xor(sfd, m);
    s1 += __shfl_xor(s1, m);
    s2 += __shfl_xor(s2, m);
  }
  if ((tid & 63) == 0) { red[wave][0] = sfd; red[wave][1] = s1; red[wave][2] = s2; }
  __syncthreads();
  if (tid == 0) {
    float a = 0.f, b2 = 0.f, c2 = 0.f;
    for (int w = 0; w < 4; ++w) { a += red[w][0]; b2 += red[w][1]; c2 += red[w][2]; }
    float* bsums = ws + WS_BSUMS;
    bsums[bid * 3 + 0] = a;
    bsums[bid * 3 + 1] = b2;
    bsums[bid * 3 + 2] = c2;
  }
}

__global__ void loss_finish3(float* __restrict__ ws, float* __restrict__ out) {
  __shared__ float s[7][3];
  const float* bsums = ws + WS_BSUMS;
  float* addterm = ws + WS_ADDT;
  int tid = threadIdx.x;
  if (tid < 21) {
    int pr = tid / 3, k = tid % 3;
    float a = 0.f;
    for (int i = 0; i < 64; ++i) a += bsums[(pr * 64 + i) * 3 + k];
    s[pr][k] = a;
  }
  __syncthreads();
  if (tid == 0) {
    const float invN = 1.f / NTOTF;
    out[OFF_PI_SCALAR] = -(s[0][1] + (s[0][0] * invN - 0.18f) * s[0][2]) * invN;
    out[OFF_PO_SCALAR] = -(s[1][1] + (s[1][0] * invN - 0.12f) * s[1][2]) * invN;
  }
  if (tid >= 1 && tid < 6) addterm[tid - 1] = s[tid + 1][0] / NTOTF - 0.46f;
}

__global__ __launch_bounds__(256) void neg_loss_kernel(
    float* __restrict__ lossr, const float* __restrict__ cdr,
    const float* __restrict__ addterm) {
  __shared__ float at[5];
  if (threadIdx.x < 5) at[threadIdx.x] = addterm[threadIdx.x];
  __syncthreads();
  const int total4 = 5 * 117128;  // 468512/4 per pair
  float4* l4 = (float4*)lossr;
  const float4* c4 = (const float4*)cdr;
  for (int e = blockIdx.x * 256 + threadIdx.x; e < total4; e += gridDim.x * 256) {
    int k = e / 117128;
    float4 cd = c4[e];
    float4 fv = l4[e];
    float a = at[k];
    float4 r;
    r.x = -fminf(fmaxf(cd.x, 0.f), 0.8f) * (fv.x + a);
    r.y = -fminf(fmaxf(cd.y, 0.f), 0.8f) * (fv.y + a);
    r.z = -fminf(fmaxf(cd.z, 0.f), 0.8f) * (fv.z + a);
    r.w = -fminf(fmaxf(cd.w, 0.f), 0.8f) * (fv.w + a);
    l4[e] = r;
  }
}

// ===================== fallback path (round-1, verified) =====================

__global__ __launch_bounds__(256) void loss_main_fb(
    const float* __restrict__ OF, const float* __restrict__ OFP,
    const float* __restrict__ OC, const float* __restrict__ OCP,
    const float* __restrict__ DAF,
    const float* __restrict__ CO1, const float* __restrict__ CO2,
    const int* __restrict__ PERMS,
    float* __restrict__ out, float* __restrict__ bsums) {
  const int b = blockIdx.x;
  const int pair = b >> 7;
  const int rem = b & 127;
  const int n = rem >> 2;
  const int rg = rem & 3;
  const int row_start = rg * 31;
  const int rcount = min(31, P - row_start);
  const int tid = threadIdx.x;
  const int tx = tid & 15, ty = tid >> 4;

  const float *F1, *F2, *C1, *C2, *CB;
  if (pair == 0) {
    F1 = DAF + (size_t)n * CF * NPIX; F2 = F1;
    C1 = OC + (size_t)n * CCODE * NPIX; C2 = C1;
    CB = CO1;
  } else if (pair == 1) {
    F1 = OF + (size_t)n * CF * NPIX; F2 = OFP + (size_t)n * CF * NPIX;
    C1 = OC + (size_t)n * CCODE * NPIX; C2 = OCP + (size_t)n * CCODE * NPIX;
    CB = CO2;
  } else {
    int n2 = PERMS[(pair - 2) * NB + n];
    F1 = OF + (size_t)n * CF * NPIX; F2 = OF + (size_t)n2 * CF * NPIX;
    C1 = OC + (size_t)n * CCODE * NPIX; C2 = OC + (size_t)n2 * CCODE * NPIX;
    CB = CO2;
  }

  __shared__ int4 Bo[P];
  __shared__ float4 Bw[P];
  __shared__ int4 Ao[32];
  __shared__ float4 Aw[32];
  __shared__ float Abuf[CCODE][32];
  __shared__ float Bbuf[CCODE][128];
  __shared__ float invA[32], invB[128];
  __shared__ float red[4][3];

  if (tid < P) {
    int gi = tid / 11, gj = tid - gi * 11;
    const float* cp = CB + (((n * 11 + gj) * 11 + gi) << 1);
    mkcoord(cp, &Bo[tid], &Bw[tid]);
  } else if (tid >= 128 && tid < 160) {
    int r = tid - 128;
    int q = row_start + r;
    if (q < P) {
      int gi = q / 11, gj = q - gi * 11;
      const float* cp = CO1 + (((n * 11 + gj) * 11 + gi) << 1);
      mkcoord(cp, &Ao[r], &Aw[r]);
    }
  }
  __syncthreads();

  float acc[2][2][4];
#pragma unroll
  for (int kr = 0; kr < 2; ++kr)
#pragma unroll
    for (int m = 0; m < 2; ++m)
#pragma unroll
      for (int u = 0; u < 4; ++u) acc[kr][m][u] = 0.f;
  float ansq = 0.f, bnsq = 0.f;

  for (int ch = 0; ch < 12; ++ch) {
    const int c0 = ch * 64;
    if (ch) __syncthreads();
    for (int e = tid; e < 64 * 128; e += 256) {
      int col = e & 127, cc = e >> 7;
      float v = 0.f;
      if (col < P) v = samp4(F2, c0 + cc, Bo[col], Bw[col]);
      Bbuf[cc][col] = v;
    }
    for (int e = tid; e < 64 * 32; e += 256) {
      int col = e & 31, cc = e >> 5;
      float v = 0.f;
      if (col < rcount) v = samp4(F1, c0 + cc, Ao[col], Aw[col]);
      Abuf[cc][col] = v;
    }
    __syncthreads();
    if (tid < 128) {
      float s = 0.f;
      for (int cc = 0; cc < 64; ++cc) { float v = Bbuf[cc][tid]; s = fmaf(v, v, s); }
      bnsq += s;
    } else if (tid < 160) {
      int r = tid - 128;
      float s = 0.f;
      for (int cc = 0; cc < 64; ++cc) { float v = Abuf[cc][r]; s = fmaf(v, v, s); }
      ansq += s;
    }
    for (int cc = 0; cc < 64; ++cc) {
      const float2 av = *(const float2*)&Abuf[cc][ty * 2];
      const float4 b0 = *(const float4*)&Bbuf[cc][tx * 4];
      const float4 b1 = *(const float4*)&Bbuf[cc][tx * 4 + 64];
      float a[2] = {av.x, av.y};
      float bb[2][4] = {{b0.x, b0.y, b0.z, b0.w}, {b1.x, b1.y, b1.z, b1.w}};
#pragma unroll
      for (int kr = 0; kr < 2; ++kr)
#pragma unroll
        for (int m = 0; m < 2; ++m)
#pragma unroll
          for (int u = 0; u < 4; ++u)
            acc[kr][m][u] = fmaf(a[kr], bb[m][u], acc[kr][m][u]);
    }
  }
  __syncthreads();
  if (tid < 128) invB[tid] = (tid < P) ? 1.f / fmaxf(sqrtf(bnsq), 1e-10f) : 0.f;
  else if (tid < 160) {
    int r = tid - 128;
    invA[r] = (r < rcount) ? 1.f / fmaxf(sqrtf(ansq), 1e-10f) : 0.f;
  }
  __syncthreads();

  float ia[2] = {invA[2 * ty], invA[2 * ty + 1]};
  float ib[2][4];
#pragma unroll
  for (int m = 0; m < 2; ++m)
#pragma unroll
    for (int u = 0; u < 4; ++u) ib[m][u] = invB[m * 64 + tx * 4 + u];

  float fdc[2][2][4];
  float sfd = 0.f;
#pragma unroll
  for (int kr = 0; kr < 2; ++kr) {
    float part = 0.f;
#pragma unroll
    for (int m = 0; m < 2; ++m)
#pragma unroll
      for (int u = 0; u < 4; ++u) {
        float v = acc[kr][m][u] * ia[kr] * ib[m][u];
        fdc[kr][m][u] = v;
        part += v;
      }
    sfd += part;
    float rs = part;
#pragma unroll
    for (int s = 1; s < 16; s <<= 1) rs += __shfl_xor(rs, s, 16);
    float rowm = rs * (1.f / 121.f);
#pragma unroll
    for (int m = 0; m < 2; ++m)
#pragma unroll
      for (int u = 0; u < 4; ++u) fdc[kr][m][u] -= rowm;
  }
  __syncthreads();

  for (int e = tid; e < CCODE * 128; e += 256) {
    int col = e & 127, cc = e >> 7;
    float v = 0.f;
    if (col < P) v = samp4(C2, cc, Bo[col], Bw[col]);
    Bbuf[cc][col] = v;
  }
  for (int e = tid; e < CCODE * 32; e += 256) {
    int col = e & 31, cc = e >> 5;
    float v = 0.f;
    if (col < rcount) v = samp4(C1, cc, Ao[col], Aw[col]);
    Abuf[cc][col] = v;
  }
  __syncthreads();
  if (tid < 128) {
    float s = 0.f;
    for (int cc = 0; cc < CCODE; ++cc) { float v = Bbuf[cc][tid]; s = fmaf(v, v, s); }
    invB[tid] = (tid < P) ? 1.f / fmaxf(sqrtf(s), 1e-10f) : 0.f;
  } else if (tid < 160) {
    int r = tid - 128;
    float s = 0.f;
    for (int cc = 0; cc < CCODE; ++cc) { float v = Abuf[cc][r]; s = fmaf(v, v, s); }
    invA[r] = (r < rcount) ? 1.f / fmaxf(sqrtf(s), 1e-10f) : 0.f;
  }
  float cacc[2][2][4];
#pragma unroll
  for (int kr = 0; kr < 2; ++kr)
#pragma unroll
    for (int m = 0; m < 2; ++m)
#pragma unroll
      for (int u = 0; u < 4; ++u) cacc[kr][m][u] = 0.f;
  for (int cc = 0; cc < CCODE; ++cc) {
    const float2 av = *(const float2*)&Abuf[cc][ty * 2];
    const float4 b0 = *(const float4*)&Bbuf[cc][tx * 4];
    const float4 b1 = *(const float4*)&Bbuf[cc][tx * 4 + 64];
    float a[2] = {av.x, av.y};
    float bb[2][4] = {{b0.x, b0.y, b0.z, b0.w}, {b1.x, b1.y, b1.z, b1.w}};
#pragma unroll
    for (int kr = 0; kr < 2; ++kr)
#pragma unroll
      for (int m = 0; m < 2; ++m)
#pragma unroll
        for (int u = 0; u < 4; ++u)
          cacc[kr][m][u] = fmaf(a[kr], bb[m][u], cacc[kr][m][u]);
  }
  __syncthreads();
  float iac[2] = {invA[2 * ty], invA[2 * ty + 1]};
  float ibc[2][4];
#pragma unroll
  for (int m = 0; m < 2; ++m)
#pragma unroll
    for (int u = 0; u < 4; ++u) ibc[m][u] = invB[m * 64 + tx * 4 + u];

  int cd_base, loss_base = 0;
  if (pair == 0) cd_base = OFF_PI_CD + n * 14641;
  else if (pair == 1) cd_base = OFF_PO_CD + n * 14641;
  else {
    int t = ((pair - 2) * NB + n) * 14641;
    cd_base = OFF_NEG_CD + t;
    loss_base = OFF_NEG_LOSS + t;
  }

  float s1 = 0.f, s2 = 0.f;
#pragma unroll
  for (int kr = 0; kr < 2; ++kr) {
    int r = 2 * ty + kr;
    if (r < rcount) {
      int rglob = row_start + r;
#pragma unroll
      for (int m = 0; m < 2; ++m)
#pragma unroll
        for (int u = 0; u < 4; ++u) {
          int c = m * 64 + tx * 4 + u;
          if (c < P) {
            float cdv = cacc[kr][m][u] * iac[kr] * ibc[m][u];
            int idx = rglob * P + c;
            out[cd_base + idx] = cdv;
            float cl = fminf(fmaxf(cdv, 0.f), 0.8f);
            float fv = fdc[kr][m][u];
            if (pair < 2) { s1 = fmaf(cl, fv, s1); s2 += cl; }
            else out[loss_base + idx] = fv;
          }
        }
    }
  }

#pragma unroll
  for (int s = 1; s < 64; s <<= 1) {
    sfd += __shfl_xor(sfd, s);
    s1 += __shfl_xor(s1, s);
    s2 += __shfl_xor(s2, s);
  }
  int wv = tid >> 6;
  if ((tid & 63) == 0) { red[wv][0] = sfd; red[wv][1] = s1; red[wv][2] = s2; }
  __syncthreads();
  if (tid == 0) {
    float a = 0.f, bb = 0.f, cc = 0.f;
    for (int w = 0; w < 4; ++w) { a += red[w][0]; bb += red[w][1]; cc += red[w][2]; }
    bsums[b * 3 + 0] = a;
    bsums[b * 3 + 1] = bb;
    bsums[b * 3 + 2] = cc;
  }
}

__global__ void loss_finish_fb(const float* __restrict__ bsums,
                               float* __restrict__ out,
                               float* __restrict__ addterm) {
  __shared__ float s[7][3];
  int tid = threadIdx.x;
  if (tid < 21) {
    int pr = tid / 3, k = tid % 3;
    float a = 0.f;
    const float* p = bsums + (pr * 128) * 3 + k;
    for (int i = 0; i < 128; ++i) a += p[i * 3];
    s[pr][k] = a;
  }
  __syncthreads();
  if (tid == 0) {
    const float invN = 1.f / NTOTF;
    out[OFF_PI_SCALAR] = -(s[0][1] + (s[0][0] * invN - 0.18f) * s[0][2]) * invN;
    out[OFF_PO_SCALAR] = -(s[1][1] + (s[1][0] * invN - 0.12f) * s[1][2]) * invN;
  }
  if (tid >= 1 && tid < 6) addterm[tid - 1] = s[tid + 1][0] / NTOTF - 0.46f;
}

__global__ __launch_bounds__(256) void neg_loss_fb(
    float* __restrict__ lossr, const float* __restrict__ cdr,
    const float* __restrict__ addterm) {
  __shared__ float at[5];
  if (threadIdx.x < 5) at[threadIdx.x] = addterm[threadIdx.x];
  __syncthreads();
  const int total = 5 * 468512;
  for (int e = blockIdx.x * 256 + threadIdx.x; e < total; e += gridDim.x * 256) {
    int k = e / 468512;
    float cdv = cdr[e];
    float cl = fminf(fmaxf(cdv, 0.f), 0.8f);
    lossr[e] = -cl * (lossr[e] + at[k]);
  }
}

extern "C" void kernel_launch(void* const* d_in, const int* in_sizes, int n_in,
                              void* d_out, int out_size, void* d_ws,
                              size_t ws_size, hipStream_t stream) {
  const float* OF = (const float*)d_in[0];
  const float* OFP = (const float*)d_in[1];
  const float* OC = (const float*)d_in[4];
  const float* OCP = (const float*)d_in[5];
  const float* DAF = (const float*)d_in[6];
  const float* CO1 = (const float*)d_in[8];
  const float* CO2 = (const float*)d_in[9];
  const int* PERMS = (const int*)d_in[10];
  float* out = (float*)d_out;
  float* ws = (float*)d_ws;

  if (ws_size >= (size_t)WS_NEED2 * sizeof(float)) {
    hipLaunchKernelGGL(presample_p3, dim3(1216), dim3(256), 0, stream,
                       OF, OFP, OC, OCP, DAF, CO1, CO2, PERMS, ws);
    hipLaunchKernelGGL(gram_mfma2, dim3(448), dim3(256), 0, stream, ws, out);
    hipLaunchKernelGGL(loss_finish3, dim3(1), dim3(64), 0, stream, ws, out);
    hipLaunchKernelGGL(neg_loss_kernel, dim3(2048), dim3(256), 0, stream,
                       out + OFF_NEG_LOSS, out + OFF_NEG_CD, ws + WS_ADDT);
  } else {
    float* bsums = ws;
    float* addterm = bsums + 896 * 3;
    hipLaunchKernelGGL(loss_main_fb, dim3(896), dim3(256), 0, stream,
                       OF, OFP, OC, OCP, DAF, CO1, CO2, PERMS, out, bsums);
    hipLaunchKernelGGL(loss_finish_fb, dim3(1), dim3(64), 0, stream,
                       bsums, out, addterm);
    hipLaunchKernelGGL(neg_loss_fb, dim3(2048), dim3(256), 0, stream,
                       out + OFF_NEG_LOSS, out + OFF_NEG_CD, addterm);
  }
}

// Round 16
// 137.299 us; speedup vs baseline: 1.0742x; 1.0742x over previous
//
#include <hip/hip_runtime.h>

#define CF 768
#define CCODE 70
#define NPIX 784
#define P 121
#define NB 32
#define NTOTF 468512.0f

#define OFF_PI_SCALAR 0
#define OFF_PI_CD 1
#define OFF_PO_SCALAR 468513
#define OFF_PO_CD 468514
#define OFF_NEG_LOSS 937026
#define OFF_NEG_CD 3279586

// ---- ws layout (floats) ----
#define WS_BSUMS 0              // 448*3
#define WS_ADDT 1536            // 5
#define WS_NSQF 2048            // 8 slots * 32 n * 12 sub * 128 pt = 393216
#define WS_NSQC 395264          // 7 slots * 32 n * 128 pt = 28672
#define WS_FRAG_FLOAT 423936    // bf16 fragment region
#define FEAT_FRAG_SHORTS 98304  // 24 panels * 8 tiles * 64 lanes * 8
#define CODE_FRAG_SHORTS 12288  // 3 panels * 8 * 64 * 8
#define FEATS_TOTAL_SHORTS (8 * 32 * FEAT_FRAG_SHORTS)
#define CODE_BASE_SHORTS FEATS_TOTAL_SHORTS
#define CODE_TOTAL_SHORTS (7 * 32 * CODE_FRAG_SHORTS)
#define WS_NEED2 (WS_FRAG_FLOAT + (FEATS_TOTAL_SHORTS + CODE_TOTAL_SHORTS) / 2)

typedef __attribute__((ext_vector_type(8))) short short8;
typedef __attribute__((ext_vector_type(4))) float f32x4;
typedef unsigned short ushort_t;
typedef unsigned int uint_t;

__device__ __forceinline__ float samp4(const float* __restrict__ img, int c,
                                       const int4 o, const float4 w) {
  const float* p = img + c * NPIX;
  return w.x * p[o.x] + w.y * p[o.y] + w.z * p[o.z] + w.w * p[o.w];
}

__device__ __forceinline__ void mkcoord(const float* cp, int4* o, float4* w) {
  float x = fminf(fmaxf(cp[0] * 27.f, 0.f), 27.f);
  float y = fminf(fmaxf(cp[1] * 27.f, 0.f), 27.f);
  float x0f = floorf(x), y0f = floorf(y);
  int x0 = (int)x0f, y0 = (int)y0f;
  int x1 = min(x0 + 1, 27), y1 = min(y0 + 1, 27);
  float wx = x - x0f, wy = y - y0f;
  *o = make_int4(y0 * 28 + x0, y0 * 28 + x1, y1 * 28 + x0, y1 * 28 + x1);
  *w = make_float4((1.f - wx) * (1.f - wy), wx * (1.f - wy),
                   (1.f - wx) * wy, wx * wy);
}

// pair-based coords: o = (row0 base, row1 base), w = (wa0, wa1, wb0, wb1)
__device__ __forceinline__ void mkcoord2(const float* cp, int2* o, float4* w) {
  float x = fminf(fmaxf(cp[0] * 27.f, 0.f), 27.f);
  float y = fminf(fmaxf(cp[1] * 27.f, 0.f), 27.f);
  float x0f = floorf(x), y0f = floorf(y);
  int x0 = (int)x0f, y0 = (int)y0f;
  int y1 = min(y0 + 1, 27);
  float wx = x - x0f, wy = y - y0f;
  bool sh = (x0 >= 27);
  int xb = sh ? 26 : x0;
  float wa0 = sh ? 0.f : (1.f - wx) * (1.f - wy);
  float wa1 = sh ? (1.f - wy) : wx * (1.f - wy);
  float wb0 = sh ? 0.f : (1.f - wx) * wy;
  float wb1 = sh ? wy : wx * wy;
  *o = make_int2(y0 * 28 + xb, y1 * 28 + xb);
  *w = make_float4(wa0, wa1, wb0, wb1);
}

__device__ __forceinline__ ushort_t f2bf(float x) {
  uint_t u = __float_as_uint(x);
  u += 0x7fffu + ((u >> 16) & 1u);
  return (ushort_t)(u >> 16);
}

// ===================== DMA presample (global_load_lds, dbuf) ================
// R14 verified configuration (138.4 us total). Block = (tensor, image m,
// group of G octets). 2x 8-plane LDS buffers double-buffered with
// global_load_lds DMA; lane-linear staging (wave-uniform LDS base + lane*16).
// Partial octets (code tensors) use manual zero-fill. Per-thread (slot,
// coord, frag-base, nsq-index) hoisted into named registers; sumsq partials
// fused (norms kernel eliminated).
// jobs: [0,384) OF G=8; [384,768) DAF G=8; [768,1152) OFP G=8;
// [1152,1184) OC G=12; [1184,1216) OCP G=12.  nsq sub = g0/8 (feat), 0 (code).
__global__ __launch_bounds__(256) void presample_dma(
    const float* __restrict__ OF, const float* __restrict__ OFP,
    const float* __restrict__ OC, const float* __restrict__ OCP,
    const float* __restrict__ DAF,
    const float* __restrict__ CO1, const float* __restrict__ CO2,
    const int* __restrict__ PERMS, float* __restrict__ ws) {
  ushort_t* frags = (ushort_t*)(ws + WS_FRAG_FLOAT);
  __shared__ float planes0[8 * NPIX];  // 25088 B
  __shared__ float planes1[8 * NPIX];  // 25088 B
  __shared__ int sh_slot[16], sh_n[16], sh_cb[16];
  __shared__ int sh_ncs;
  const int job = (int)(((long long)blockIdx.x * 405) % 1216);
  const int tid = threadIdx.x;
  const int wv64 = tid >> 6;

  int tensor, m, g0, G;
  if (job < 384) { tensor = 0; m = job / 12; g0 = (job - m * 12) * 8; G = 8; }
  else if (job < 768) { int j = job - 384; tensor = 1; m = j / 12; g0 = (j - m * 12) * 8; G = 8; }
  else if (job < 1152) { int j = job - 768; tensor = 2; m = j / 12; g0 = (j - m * 12) * 8; G = 8; }
  else if (job < 1184) { tensor = 3; m = job - 1152; g0 = 0; G = 12; }
  else { tensor = 4; m = job - 1184; g0 = 0; G = 12; }

  const float* src;
  int nch;
  bool feat;
  if (tensor == 0) { src = OF + (size_t)m * CF * NPIX; nch = CF; feat = true; }
  else if (tensor == 1) { src = DAF + (size_t)m * CF * NPIX; nch = CF; feat = true; }
  else if (tensor == 2) { src = OFP + (size_t)m * CF * NPIX; nch = CF; feat = true; }
  else if (tensor == 3) { src = OC + (size_t)m * CCODE * NPIX; nch = CCODE; feat = false; }
  else { src = OCP + (size_t)m * CCODE * NPIX; nch = CCODE; feat = false; }

  // ---- stage one octet: DMA when fully valid, manual zero-fill otherwise ----
#define STAGE(OCT, PL)                                                        \
  {                                                                           \
    const int c0_ = (OCT) * 8;                                                \
    const float4* sc_ = (const float4*)(src + (size_t)c0_ * NPIX);            \
    float4* pb_ = (float4*)(PL);                                              \
    if (c0_ + 8 <= nch) {                                                     \
      _Pragma("unroll") for (int k_ = 0; k_ < 6; ++k_) {                      \
        __builtin_amdgcn_global_load_lds(                                     \
            (const __attribute__((address_space(1))) uint_t*)(const void*)    \
                (sc_ + k_ * 256 + tid),                                       \
            (__attribute__((address_space(3))) uint_t*)(void*)                \
                (pb_ + k_ * 256 + wv64 * 64),                                 \
            16, 0, 0);                                                        \
      }                                                                       \
      if (tid < 32) {                                                         \
        __builtin_amdgcn_global_load_lds(                                     \
            (const __attribute__((address_space(1))) uint_t*)(const void*)    \
                (sc_ + 1536 + tid),                                           \
            (__attribute__((address_space(3))) uint_t*)(void*)(pb_ + 1536),   \
            16, 0, 0);                                                        \
      }                                                                       \
    } else {                                                                  \
      int valid_ = nch - c0_;                                                 \
      valid_ = valid_ > 8 ? 8 : (valid_ < 0 ? 0 : valid_);                    \
      const int lim4_ = valid_ * (NPIX / 4);                                  \
      _Pragma("unroll") for (int k_ = 0; k_ < 7; ++k_) {                      \
        const int e_ = tid + k_ * 256;                                        \
        if (e_ < 1568)                                                        \
          pb_[e_] = (e_ < lim4_) ? sc_[e_] : make_float4(0.f, 0.f, 0.f, 0.f); \
      }                                                                       \
    }                                                                         \
  }

  STAGE(g0, planes0);

  if (tid == 0) {
    int cnt = 0;
    if (tensor == 0) {
      sh_slot[0] = 1; sh_n[0] = m; sh_cb[0] = 0; cnt = 1;
      for (int i = 0; i < 5; ++i)
        for (int k = 0; k < NB; ++k)
          if (PERMS[i * NB + k] == m) {
            sh_slot[cnt] = 3 + i; sh_n[cnt] = k; sh_cb[cnt] = 1; ++cnt;
          }
    } else if (tensor == 1) { sh_slot[0] = 0; sh_n[0] = m; sh_cb[0] = 0; cnt = 1; }
    else if (tensor == 2) { sh_slot[0] = 2; sh_n[0] = m; sh_cb[0] = 1; cnt = 1; }
    else if (tensor == 3) {
      sh_slot[0] = 0; sh_n[0] = m; sh_cb[0] = 0; cnt = 1;
      for (int i = 0; i < 5; ++i)
        for (int k = 0; k < NB; ++k)
          if (PERMS[i * NB + k] == m) {
            sh_slot[cnt] = 2 + i; sh_n[cnt] = k; sh_cb[cnt] = 1; ++cnt;
          }
    } else { sh_slot[0] = 1; sh_n[0] = m; sh_cb[0] = 1; cnt = 1; }
    sh_ncs = cnt;
  }
  __syncthreads();  // publish sh list + drain first-octet DMA

  const int total = sh_ncs * 128;
  const int sub = g0 >> 3;
  int2 o_0, o_1, o_2, o_3, o_4, o_5;
  float4 w_0, w_1, w_2, w_3, w_4, w_5;
  uint_t b_0 = 0, b_1 = 0, b_2 = 0, b_3 = 0, b_4 = 0, b_5 = 0;
  uint_t nq_0 = 0, nq_1 = 0, nq_2 = 0, nq_3 = 0, nq_4 = 0, nq_5 = 0;
  float sq_0 = 0.f, sq_1 = 0.f, sq_2 = 0.f, sq_3 = 0.f, sq_4 = 0.f, sq_5 = 0.f;
#define SETUP_SLOT(J, OV, WV, BV, NQV)                                       \
  {                                                                          \
    const int s_ = tid + (J) * 256;                                          \
    OV = make_int2(0, 0);                                                    \
    WV = make_float4(0.f, 0.f, 0.f, 0.f);                                    \
    if (s_ < total) {                                                        \
      const int cs_ = s_ >> 7, pt_ = s_ & 127;                               \
      const int slot_ = sh_slot[cs_], n_ = sh_n[cs_];                        \
      const float* cb_ = sh_cb[cs_] ? CO2 : CO1;                             \
      size_t fb_ = feat ? (size_t)(slot_ * 32 + n_) * FEAT_FRAG_SHORTS       \
                        : CODE_BASE_SHORTS +                                 \
                              (size_t)(slot_ * 32 + n_) * CODE_FRAG_SHORTS;  \
      BV = (uint_t)(fb_ + ((size_t)((pt_ >> 4) * 64 + (pt_ & 15)) << 3));    \
      NQV = feat ? (uint_t)(WS_NSQF +                                        \
                            ((slot_ * 32 + n_) * 12 + sub) * 128 + pt_)      \
                 : (uint_t)(WS_NSQC + (slot_ * 32 + n_) * 128 + pt_);        \
      if (pt_ < P) {                                                         \
        int gi_ = pt_ / 11, gj_ = pt_ - gi_ * 11;                            \
        mkcoord2(cb_ + (((n_ * 11 + gj_) * 11 + gi_) << 1), &OV, &WV);       \
      }                                                                      \
    }                                                                        \
  }
  SETUP_SLOT(0, o_0, w_0, b_0, nq_0)
  SETUP_SLOT(1, o_1, w_1, b_1, nq_1)
  SETUP_SLOT(2, o_2, w_2, b_2, nq_2)
  SETUP_SLOT(3, o_3, w_3, b_3, nq_3)
  SETUP_SLOT(4, o_4, w_4, b_4, nq_4)
  SETUP_SLOT(5, o_5, w_5, b_5, nq_5)
#undef SETUP_SLOT

#define DO_SLOT(J, OV, WV, BV, SQV)                                          \
  if (tid + (J) * 256 < total) {                                             \
    float v_[8];                                                             \
    _Pragma("unroll") for (int i_ = 0; i_ < 8; ++i_) {                       \
      const float* pl_ = PL + i_ * NPIX;                                     \
      v_[i_] = WV.x * pl_[OV.x] + WV.y * pl_[OV.x + 1] +                     \
               WV.z * pl_[OV.y] + WV.w * pl_[OV.y + 1];                      \
      SQV = fmaf(v_[i_], v_[i_], SQV);                                       \
    }                                                                        \
    uint4 q_;                                                                \
    q_.x = (uint_t)f2bf(v_[0]) | ((uint_t)f2bf(v_[1]) << 16);                \
    q_.y = (uint_t)f2bf(v_[2]) | ((uint_t)f2bf(v_[3]) << 16);                \
    q_.z = (uint_t)f2bf(v_[4]) | ((uint_t)f2bf(v_[5]) << 16);                \
    q_.w = (uint_t)f2bf(v_[6]) | ((uint_t)f2bf(v_[7]) << 16);                \
    *(uint4*)(frags + BV + octoff) = q_;                                     \
  }

  for (int g = 0; g < G; ++g) {
    const int o = g0 + g;
    const float* PL = (g & 1) ? planes1 : planes0;
    float* PN = (g & 1) ? planes0 : planes1;
    if (g + 1 < G) STAGE(g0 + g + 1, PN);  // DMA in flight during sampling

    const uint_t octoff = (uint_t)((o >> 2) * 4096 + (o & 3) * 128);
    DO_SLOT(0, o_0, w_0, b_0, sq_0)
    DO_SLOT(1, o_1, w_1, b_1, sq_1)
    DO_SLOT(2, o_2, w_2, b_2, sq_2)
    DO_SLOT(3, o_3, w_3, b_3, sq_3)
    DO_SLOT(4, o_4, w_4, b_4, sq_4)
    DO_SLOT(5, o_5, w_5, b_5, sq_5)
    __syncthreads();  // drain next-octet DMA + all sampling of PL done
  }
#undef DO_SLOT
#undef STAGE

  // ---- write per-slot sumsq partials (each written exactly once) ----
  if (tid < total) ws[nq_0] = sq_0;
  if (tid + 256 < total) ws[nq_1] = sq_1;
  if (tid + 512 < total) ws[nq_2] = sq_2;
  if (tid + 768 < total) ws[nq_3] = sq_3;
  if (tid + 1024 < total) ws[nq_4] = sq_4;
  if (tid + 1280 < total) ws[nq_5] = sq_5;
}

// ===================== MFMA Gram (448 blocks = pairn x 2 row-halves) ========
__global__ __launch_bounds__(256) void gram_mfma2(float* __restrict__ ws,
                                                  float* __restrict__ out) {
  const ushort_t* frags = (const ushort_t*)(ws + WS_FRAG_FLOAT);
  const int bid = blockIdx.x;
  const int half = bid & 1, pairn = bid >> 1;
  const int pair = pairn >> 5, n = pairn & 31;
  const int tid = threadIdx.x, wave = tid >> 6, lane = tid & 63;
  __shared__ float invAf[128], invBf[128], invAc[128], invBc[128];
  __shared__ float red[4][3];
  const int afslot = (pair == 0) ? 0 : 1;
  const int bfslot = (pair == 0) ? 0 : (pair == 1 ? 2 : 3 + (pair - 2));
  const int bcslot = (pair == 0) ? 0 : (pair == 1 ? 1 : 2 + (pair - 2));
  if (tid < 128) {
    float s;
    const float* p;
    p = ws + WS_NSQF + (size_t)(afslot * 32 + n) * 12 * 128 + tid;
    s = 0.f;
#pragma unroll
    for (int u = 0; u < 12; ++u) s += p[u * 128];
    invAf[tid] = 1.f / fmaxf(sqrtf(s), 1e-10f);
    p = ws + WS_NSQF + (size_t)(bfslot * 32 + n) * 12 * 128 + tid;
    s = 0.f;
#pragma unroll
    for (int u = 0; u < 12; ++u) s += p[u * 128];
    invBf[tid] = 1.f / fmaxf(sqrtf(s), 1e-10f);
    invAc[tid] = 1.f / fmaxf(sqrtf(ws[WS_NSQC + (0 * 32 + n) * 128 + tid]), 1e-10f);
    invBc[tid] = 1.f / fmaxf(sqrtf(ws[WS_NSQC + (bcslot * 32 + n) * 128 + tid]), 1e-10f);
  }
  __syncthreads();

  const short8* Af = (const short8*)(frags + (size_t)(afslot * 32 + n) * FEAT_FRAG_SHORTS);
  const short8* Bf = (const short8*)(frags + (size_t)(bfslot * 32 + n) * FEAT_FRAG_SHORTS);
  const int rt = half * 4 + wave;  // row-tile 0..7

  f32x4 acc[8];
#pragma unroll
  for (int t = 0; t < 8; ++t) acc[t] = (f32x4){0.f, 0.f, 0.f, 0.f};

#pragma unroll 2
  for (int kp = 0; kp < 24; ++kp) {
    short8 a0 = Af[(kp * 8 + rt) * 64 + lane];
    short8 bv[8];
#pragma unroll
    for (int t = 0; t < 8; ++t) bv[t] = Bf[(kp * 8 + t) * 64 + lane];
#pragma unroll
    for (int t = 0; t < 8; ++t)
      acc[t] = __builtin_amdgcn_mfma_f32_16x16x32_bf16(a0, bv[t], acc[t], 0, 0, 0);
  }

  const int lane4 = (lane >> 4) << 2;
  const int cl15 = lane & 15;
  const int rb = rt * 16 + lane4;
  float sfd = 0.f;
  {
    const float ivr0 = invAf[rb], ivr1 = invAf[rb + 1], ivr2 = invAf[rb + 2],
                ivr3 = invAf[rb + 3];
    float rs0 = 0.f, rs1 = 0.f, rs2 = 0.f, rs3 = 0.f;
#pragma unroll
    for (int t = 0; t < 8; ++t) {
      const float ivc = invBf[t * 16 + cl15];
      float v0 = acc[t].x * ivr0 * ivc;
      float v1 = acc[t].y * ivr1 * ivc;
      float v2 = acc[t].z * ivr2 * ivc;
      float v3 = acc[t].w * ivr3 * ivc;
      acc[t].x = v0; acc[t].y = v1; acc[t].z = v2; acc[t].w = v3;
      rs0 += v0; rs1 += v1; rs2 += v2; rs3 += v3;
    }
    sfd = rs0 + rs1 + rs2 + rs3;
    rs0 += __shfl_xor(rs0, 1); rs0 += __shfl_xor(rs0, 2);
    rs0 += __shfl_xor(rs0, 4); rs0 += __shfl_xor(rs0, 8);
    rs1 += __shfl_xor(rs1, 1); rs1 += __shfl_xor(rs1, 2);
    rs1 += __shfl_xor(rs1, 4); rs1 += __shfl_xor(rs1, 8);
    rs2 += __shfl_xor(rs2, 1); rs2 += __shfl_xor(rs2, 2);
    rs2 += __shfl_xor(rs2, 4); rs2 += __shfl_xor(rs2, 8);
    rs3 += __shfl_xor(rs3, 1); rs3 += __shfl_xor(rs3, 2);
    rs3 += __shfl_xor(rs3, 4); rs3 += __shfl_xor(rs3, 8);
    const float rm0 = rs0 * (1.f / 121.f), rm1 = rs1 * (1.f / 121.f);
    const float rm2 = rs2 * (1.f / 121.f), rm3 = rs3 * (1.f / 121.f);
#pragma unroll
    for (int t = 0; t < 8; ++t) {
      acc[t].x -= rm0; acc[t].y -= rm1; acc[t].z -= rm2; acc[t].w -= rm3;
    }
  }

  int cd_base, loss_base = 0;
  if (pair == 0) cd_base = OFF_PI_CD + n * 14641;
  else if (pair == 1) cd_base = OFF_PO_CD + n * 14641;
  else {
    int t0 = ((pair - 2) * NB + n) * 14641;
    cd_base = OFF_NEG_CD + t0;
    loss_base = OFF_NEG_LOSS + t0;
  }

  if (pair >= 2 && rb < P) {
#pragma unroll
    for (int t = 0; t < 8; ++t) {
      const int c = t * 16 + cl15;
      if (c < P) {
        float* o = out + loss_base + rb * P + c;
        o[0] = acc[t].x;
        if (rb + 1 < P) o[P] = acc[t].y;
        if (rb + 2 < P) o[2 * P] = acc[t].z;
        if (rb + 3 < P) o[3 * P] = acc[t].w;
      }
    }
  }

  // ---- code Gram (this half's rows) ----
  const short8* Ac = (const short8*)(frags + CODE_BASE_SHORTS + (size_t)n * CODE_FRAG_SHORTS);
  const short8* Bc = (const short8*)(frags + CODE_BASE_SHORTS + (size_t)(bcslot * 32 + n) * CODE_FRAG_SHORTS);
  f32x4 cacc[8];
#pragma unroll
  for (int t = 0; t < 8; ++t) cacc[t] = (f32x4){0.f, 0.f, 0.f, 0.f};
#pragma unroll
  for (int kp = 0; kp < 3; ++kp) {
    short8 a0 = Ac[(kp * 8 + rt) * 64 + lane];
    short8 bv[8];
#pragma unroll
    for (int t = 0; t < 8; ++t) bv[t] = Bc[(kp * 8 + t) * 64 + lane];
#pragma unroll
    for (int t = 0; t < 8; ++t)
      cacc[t] = __builtin_amdgcn_mfma_f32_16x16x32_bf16(a0, bv[t], cacc[t], 0, 0, 0);
  }

  float s1 = 0.f, s2 = 0.f;
  {
    const float ivr0 = invAc[rb], ivr1 = invAc[rb + 1], ivr2 = invAc[rb + 2],
                ivr3 = invAc[rb + 3];
#pragma unroll
    for (int t = 0; t < 8; ++t) {
      const int c = t * 16 + cl15;
      const float ivc = invBc[c];
      float c0v = cacc[t].x * ivr0 * ivc;
      float c1v = cacc[t].y * ivr1 * ivc;
      float c2v = cacc[t].z * ivr2 * ivc;
      float c3v = cacc[t].w * ivr3 * ivc;
      if (c < P && rb < P) {
        float* o = out + cd_base + rb * P + c;
        o[0] = c0v;
        if (rb + 1 < P) o[P] = c1v;
        if (rb + 2 < P) o[2 * P] = c2v;
        if (rb + 3 < P) o[3 * P] = c3v;
      }
      if (pair < 2) {
        float cl0 = fminf(fmaxf(c0v, 0.f), 0.8f);
        float cl1 = fminf(fmaxf(c1v, 0.f), 0.8f);
        float cl2 = fminf(fmaxf(c2v, 0.f), 0.8f);
        float cl3 = fminf(fmaxf(c3v, 0.f), 0.8f);
        s1 = fmaf(cl0, acc[t].x, s1);
        s1 = fmaf(cl1, acc[t].y, s1);
        s1 = fmaf(cl2, acc[t].z, s1);
        s1 = fmaf(cl3, acc[t].w, s1);
        s2 += cl0 + cl1 + cl2 + cl3;
      }
    }
  }

#pragma unroll
  for (int m = 1; m < 64; m <<= 1) {
    sfd += __shfl_xor(sfd, m);
    s1 += __shfl_xor(s1, m);
    s2 += __shfl_xor(s2, m);
  }
  if ((tid & 63) == 0) { red[wave][0] = sfd; red[wave][1] = s1; red[wave][2] = s2; }
  __syncthreads();
  if (tid == 0) {
    float a = 0.f, b2 = 0.f, c2 = 0.f;
    for (int w = 0; w < 4; ++w) { a += red[w][0]; b2 += red[w][1]; c2 += red[w][2]; }
    float* bsums = ws + WS_BSUMS;
    bsums[bid * 3 + 0] = a;
    bsums[bid * 3 + 1] = b2;
    bsums[bid * 3 + 2] = c2;
  }
}

__global__ void loss_finish3(float* __restrict__ ws, float* __restrict__ out) {
  __shared__ float s[7][3];
  const float* bsums = ws + WS_BSUMS;
  float* addterm = ws + WS_ADDT;
  int tid = threadIdx.x;
  if (tid < 21) {
    int pr = tid / 3, k = tid % 3;
    float a = 0.f;
    for (int i = 0; i < 64; ++i) a += bsums[(pr * 64 + i) * 3 + k];
    s[pr][k] = a;
  }
  __syncthreads();
  if (tid == 0) {
    const float invN = 1.f / NTOTF;
    out[OFF_PI_SCALAR] = -(s[0][1] + (s[0][0] * invN - 0.18f) * s[0][2]) * invN;
    out[OFF_PO_SCALAR] = -(s[1][1] + (s[1][0] * invN - 0.12f) * s[1][2]) * invN;
  }
  if (tid >= 1 && tid < 6) addterm[tid - 1] = s[tid + 1][0] / NTOTF - 0.46f;
}

__global__ __launch_bounds__(256) void neg_loss_kernel(
    float* __restrict__ lossr, const float* __restrict__ cdr,
    const float* __restrict__ addterm) {
  __shared__ float at[5];
  if (threadIdx.x < 5) at[threadIdx.x] = addterm[threadIdx.x];
  __syncthreads();
  const int total4 = 5 * 117128;  // 468512/4 per pair
  float4* l4 = (float4*)lossr;
  const float4* c4 = (const float4*)cdr;
  for (int e = blockIdx.x * 256 + threadIdx.x; e < total4; e += gridDim.x * 256) {
    int k = e / 117128;
    float4 cd = c4[e];
    float4 fv = l4[e];
    float a = at[k];
    float4 r;
    r.x = -fminf(fmaxf(cd.x, 0.f), 0.8f) * (fv.x + a);
    r.y = -fminf(fmaxf(cd.y, 0.f), 0.8f) * (fv.y + a);
    r.z = -fminf(fmaxf(cd.z, 0.f), 0.8f) * (fv.z + a);
    r.w = -fminf(fmaxf(cd.w, 0.f), 0.8f) * (fv.w + a);
    l4[e] = r;
  }
}

// ===================== fallback path (round-1, verified) =====================

__global__ __launch_bounds__(256) void loss_main_fb(
    const float* __restrict__ OF, const float* __restrict__ OFP,
    const float* __restrict__ OC, const float* __restrict__ OCP,
    const float* __restrict__ DAF,
    const float* __restrict__ CO1, const float* __restrict__ CO2,
    const int* __restrict__ PERMS,
    float* __restrict__ out, float* __restrict__ bsums) {
  const int b = blockIdx.x;
  const int pair = b >> 7;
  const int rem = b & 127;
  const int n = rem >> 2;
  const int rg = rem & 3;
  const int row_start = rg * 31;
  const int rcount = min(31, P - row_start);
  const int tid = threadIdx.x;
  const int tx = tid & 15, ty = tid >> 4;

  const float *F1, *F2, *C1, *C2, *CB;
  if (pair == 0) {
    F1 = DAF + (size_t)n * CF * NPIX; F2 = F1;
    C1 = OC + (size_t)n * CCODE * NPIX; C2 = C1;
    CB = CO1;
  } else if (pair == 1) {
    F1 = OF + (size_t)n * CF * NPIX; F2 = OFP + (size_t)n * CF * NPIX;
    C1 = OC + (size_t)n * CCODE * NPIX; C2 = OCP + (size_t)n * CCODE * NPIX;
    CB = CO2;
  } else {
    int n2 = PERMS[(pair - 2) * NB + n];
    F1 = OF + (size_t)n * CF * NPIX; F2 = OF + (size_t)n2 * CF * NPIX;
    C1 = OC + (size_t)n * CCODE * NPIX; C2 = OC + (size_t)n2 * CCODE * NPIX;
    CB = CO2;
  }

  __shared__ int4 Bo[P];
  __shared__ float4 Bw[P];
  __shared__ int4 Ao[32];
  __shared__ float4 Aw[32];
  __shared__ float Abuf[CCODE][32];
  __shared__ float Bbuf[CCODE][128];
  __shared__ float invA[32], invB[128];
  __shared__ float red[4][3];

  if (tid < P) {
    int gi = tid / 11, gj = tid - gi * 11;
    const float* cp = CB + (((n * 11 + gj) * 11 + gi) << 1);
    mkcoord(cp, &Bo[tid], &Bw[tid]);
  } else if (tid >= 128 && tid < 160) {
    int r = tid - 128;
    int q = row_start + r;
    if (q < P) {
      int gi = q / 11, gj = q - gi * 11;
      const float* cp = CO1 + (((n * 11 + gj) * 11 + gi) << 1);
      mkcoord(cp, &Ao[r], &Aw[r]);
    }
  }
  __syncthreads();

  float acc[2][2][4];
#pragma unroll
  for (int kr = 0; kr < 2; ++kr)
#pragma unroll
    for (int m = 0; m < 2; ++m)
#pragma unroll
      for (int u = 0; u < 4; ++u) acc[kr][m][u] = 0.f;
  float ansq = 0.f, bnsq = 0.f;

  for (int ch = 0; ch < 12; ++ch) {
    const int c0 = ch * 64;
    if (ch) __syncthreads();
    for (int e = tid; e < 64 * 128; e += 256) {
      int col = e & 127, cc = e >> 7;
      float v = 0.f;
      if (col < P) v = samp4(F2, c0 + cc, Bo[col], Bw[col]);
      Bbuf[cc][col] = v;
    }
    for (int e = tid; e < 64 * 32; e += 256) {
      int col = e & 31, cc = e >> 5;
      float v = 0.f;
      if (col < rcount) v = samp4(F1, c0 + cc, Ao[col], Aw[col]);
      Abuf[cc][col] = v;
    }
    __syncthreads();
    if (tid < 128) {
      float s = 0.f;
      for (int cc = 0; cc < 64; ++cc) { float v = Bbuf[cc][tid]; s = fmaf(v, v, s); }
      bnsq += s;
    } else if (tid < 160) {
      int r = tid - 128;
      float s = 0.f;
      for (int cc = 0; cc < 64; ++cc) { float v = Abuf[cc][r]; s = fmaf(v, v, s); }
      ansq += s;
    }
    for (int cc = 0; cc < 64; ++cc) {
      const float2 av = *(const float2*)&Abuf[cc][ty * 2];
      const float4 b0 = *(const float4*)&Bbuf[cc][tx * 4];
      const float4 b1 = *(const float4*)&Bbuf[cc][tx * 4 + 64];
      float a[2] = {av.x, av.y};
      float bb[2][4] = {{b0.x, b0.y, b0.z, b0.w}, {b1.x, b1.y, b1.z, b1.w}};
#pragma unroll
      for (int kr = 0; kr < 2; ++kr)
#pragma unroll
        for (int m = 0; m < 2; ++m)
#pragma unroll
          for (int u = 0; u < 4; ++u)
            acc[kr][m][u] = fmaf(a[kr], bb[m][u], acc[kr][m][u]);
    }
  }
  __syncthreads();
  if (tid < 128) invB[tid] = (tid < P) ? 1.f / fmaxf(sqrtf(bnsq), 1e-10f) : 0.f;
  else if (tid < 160) {
    int r = tid - 128;
    invA[r] = (r < rcount) ? 1.f / fmaxf(sqrtf(ansq), 1e-10f) : 0.f;
  }
  __syncthreads();

  float ia[2] = {invA[2 * ty], invA[2 * ty + 1]};
  float ib[2][4];
#pragma unroll
  for (int m = 0; m < 2; ++m)
#pragma unroll
    for (int u = 0; u < 4; ++u) ib[m][u] = invB[m * 64 + tx * 4 + u];

  float fdc[2][2][4];
  float sfd = 0.f;
#pragma unroll
  for (int kr = 0; kr < 2; ++kr) {
    float part = 0.f;
#pragma unroll
    for (int m = 0; m < 2; ++m)
#pragma unroll
      for (int u = 0; u < 4; ++u) {
        float v = acc[kr][m][u] * ia[kr] * ib[m][u];
        fdc[kr][m][u] = v;
        part += v;
      }
    sfd += part;
    float rs = part;
#pragma unroll
    for (int s = 1; s < 16; s <<= 1) rs += __shfl_xor(rs, s, 16);
    float rowm = rs * (1.f / 121.f);
#pragma unroll
    for (int m = 0; m < 2; ++m)
#pragma unroll
      for (int u = 0; u < 4; ++u) fdc[kr][m][u] -= rowm;
  }
  __syncthreads();

  for (int e = tid; e < CCODE * 128; e += 256) {
    int col = e & 127, cc = e >> 7;
    float v = 0.f;
    if (col < P) v = samp4(C2, cc, Bo[col], Bw[col]);
    Bbuf[cc][col] = v;
  }
  for (int e = tid; e < CCODE * 32; e += 256) {
    int col = e & 31, cc = e >> 5;
    float v = 0.f;
    if (col < rcount) v = samp4(C1, cc, Ao[col], Aw[col]);
    Abuf[cc][col] = v;
  }
  __syncthreads();
  if (tid < 128) {
    float s = 0.f;
    for (int cc = 0; cc < CCODE; ++cc) { float v = Bbuf[cc][tid]; s = fmaf(v, v, s); }
    invB[tid] = (tid < P) ? 1.f / fmaxf(sqrtf(s), 1e-10f) : 0.f;
  } else if (tid < 160) {
    int r = tid - 128;
    float s = 0.f;
    for (int cc = 0; cc < CCODE; ++cc) { float v = Abuf[cc][r]; s = fmaf(v, v, s); }
    invA[r] = (r < rcount) ? 1.f / fmaxf(sqrtf(s), 1e-10f) : 0.f;
  }
  float cacc[2][2][4];
#pragma unroll
  for (int kr = 0; kr < 2; ++kr)
#pragma unroll
    for (int m = 0; m < 2; ++m)
#pragma unroll
      for (int u = 0; u < 4; ++u) cacc[kr][m][u] = 0.f;
  for (int cc = 0; cc < CCODE; ++cc) {
    const float2 av = *(const float2*)&Abuf[cc][ty * 2];
    const float4 b0 = *(const float4*)&Bbuf[cc][tx * 4];
    const float4 b1 = *(const float4*)&Bbuf[cc][tx * 4 + 64];
    float a[2] = {av.x, av.y};
    float bb[2][4] = {{b0.x, b0.y, b0.z, b0.w}, {b1.x, b1.y, b1.z, b1.w}};
#pragma unroll
    for (int kr = 0; kr < 2; ++kr)
#pragma unroll
      for (int m = 0; m < 2; ++m)
#pragma unroll
        for (int u = 0; u < 4; ++u)
          cacc[kr][m][u] = fmaf(a[kr], bb[m][u], cacc[kr][m][u]);
  }
  __syncthreads();
  float iac[2] = {invA[2 * ty], invA[2 * ty + 1]};
  float ibc[2][4];
#pragma unroll
  for (int m = 0; m < 2; ++m)
#pragma unroll
    for (int u = 0; u < 4; ++u) ibc[m][u] = invB[m * 64 + tx * 4 + u];

  int cd_base, loss_base = 0;
  if (pair == 0) cd_base = OFF_PI_CD + n * 14641;
  else if (pair == 1) cd_base = OFF_PO_CD + n * 14641;
  else {
    int t = ((pair - 2) * NB + n) * 14641;
    cd_base = OFF_NEG_CD + t;
    loss_base = OFF_NEG_LOSS + t;
  }

  float s1 = 0.f, s2 = 0.f;
#pragma unroll
  for (int kr = 0; kr < 2; ++kr) {
    int r = 2 * ty + kr;
    if (r < rcount) {
      int rglob = row_start + r;
#pragma unroll
      for (int m = 0; m < 2; ++m)
#pragma unroll
        for (int u = 0; u < 4; ++u) {
          int c = m * 64 + tx * 4 + u;
          if (c < P) {
            float cdv = cacc[kr][m][u] * iac[kr] * ibc[m][u];
            int idx = rglob * P + c;
            out[cd_base + idx] = cdv;
            float cl = fminf(fmaxf(cdv, 0.f), 0.8f);
            float fv = fdc[kr][m][u];
            if (pair < 2) { s1 = fmaf(cl, fv, s1); s2 += cl; }
            else out[loss_base + idx] = fv;
          }
        }
    }
  }

#pragma unroll
  for (int s = 1; s < 64; s <<= 1) {
    sfd += __shfl_xor(sfd, s);
    s1 += __shfl_xor(s1, s);
    s2 += __shfl_xor(s2, s);
  }
  int wv = tid >> 6;
  if ((tid & 63) == 0) { red[wv][0] = sfd; red[wv][1] = s1; red[wv][2] = s2; }
  __syncthreads();
  if (tid == 0) {
    float a = 0.f, bb = 0.f, cc = 0.f;
    for (int w = 0; w < 4; ++w) { a += red[w][0]; bb += red[w][1]; cc += red[w][2]; }
    bsums[b * 3 + 0] = a;
    bsums[b * 3 + 1] = bb;
    bsums[b * 3 + 2] = cc;
  }
}

__global__ void loss_finish_fb(const float* __restrict__ bsums,
                               float* __restrict__ out,
                               float* __restrict__ addterm) {
  __shared__ float s[7][3];
  int tid = threadIdx.x;
  if (tid < 21) {
    int pr = tid / 3, k = tid % 3;
    float a = 0.f;
    const float* p = bsums + (pr * 128) * 3 + k;
    for (int i = 0; i < 128; ++i) a += p[i * 3];
    s[pr][k] = a;
  }
  __syncthreads();
  if (tid == 0) {
    const float invN = 1.f / NTOTF;
    out[OFF_PI_SCALAR] = -(s[0][1] + (s[0][0] * invN - 0.18f) * s[0][2]) * invN;
    out[OFF_PO_SCALAR] = -(s[1][1] + (s[1][0] * invN - 0.12f) * s[1][2]) * invN;
  }
  if (tid >= 1 && tid < 6) addterm[tid - 1] = s[tid + 1][0] / NTOTF - 0.46f;
}

__global__ __launch_bounds__(256) void neg_loss_fb(
    float* __restrict__ lossr, const float* __restrict__ cdr,
    const float* __restrict__ addterm) {
  __shared__ float at[5];
  if (threadIdx.x < 5) at[threadIdx.x] = addterm[threadIdx.x];
  __syncthreads();
  const int total = 5 * 468512;
  for (int e = blockIdx.x * 256 + threadIdx.x; e < total; e += gridDim.x * 256) {
    int k = e / 468512;
    float cdv = cdr[e];
    float cl = fminf(fmaxf(cdv, 0.f), 0.8f);
    lossr[e] = -cl * (lossr[e] + at[k]);
  }
}

extern "C" void kernel_launch(void* const* d_in, const int* in_sizes, int n_in,
                              void* d_out, int out_size, void* d_ws,
                              size_t ws_size, hipStream_t stream) {
  const float* OF = (const float*)d_in[0];
  const float* OFP = (const float*)d_in[1];
  const float* OC = (const float*)d_in[4];
  const float* OCP = (const float*)d_in[5];
  const float* DAF = (const float*)d_in[6];
  const float* CO1 = (const float*)d_in[8];
  const float* CO2 = (const float*)d_in[9];
  const int* PERMS = (const int*)d_in[10];
  float* out = (float*)d_out;
  float* ws = (float*)d_ws;

  if (ws_size >= (size_t)WS_NEED2 * sizeof(float)) {
    hipLaunchKernelGGL(presample_dma, dim3(1216), dim3(256), 0, stream,
                       OF, OFP, OC, OCP, DAF, CO1, CO2, PERMS, ws);
    hipLaunchKernelGGL(gram_mfma2, dim3(448), dim3(256), 0, stream, ws, out);
    hipLaunchKernelGGL(loss_finish3, dim3(1), dim3(64), 0, stream, ws, out);
    hipLaunchKernelGGL(neg_loss_kernel, dim3(2048), dim3(256), 0, stream,
                       out + OFF_NEG_LOSS, out + OFF_NEG_CD, ws + WS_ADDT);
  } else {
    float* bsums = ws;
    float* addterm = bsums + 896 * 3;
    hipLaunchKernelGGL(loss_main_fb, dim3(896), dim3(256), 0, stream,
                       OF, OFP, OC, OCP, DAF, CO1, CO2, PERMS, out, bsums);
    hipLaunchKernelGGL(loss_finish_fb, dim3(1), dim3(64), 0, stream,
                       bsums, out, addterm);
    hipLaunchKernelGGL(neg_loss_fb, dim3(2048), dim3(256), 0, stream,
                       out + OFF_NEG_LOSS, out + OFF_NEG_CD, addterm);
  }
}